// Round 3
// baseline (5094.932 us; speedup 1.0000x reference)
//
#include <hip/hip_runtime.h>

typedef unsigned short u16;
typedef __attribute__((ext_vector_type(8))) short short8;
typedef __attribute__((ext_vector_type(4))) float f32x4;

union U16x8 { uint4 u; short8 s; u16 h[8]; };

__device__ __forceinline__ float b2f(u16 u) {
  union { unsigned int i; float f; } x; x.i = ((unsigned int)u) << 16; return x.f;
}
__device__ __forceinline__ u16 f2b(float f) {
  union { float f; unsigned int i; } x; x.f = f;
  unsigned int r = x.i + 0x7FFFu + ((x.i >> 16) & 1u);
  return (u16)(r >> 16);
}
__device__ __forceinline__ float sig_(float x) { return 1.0f / (1.0f + __expf(-x)); }
__device__ __forceinline__ float tanh_(float x) {
  float e = __expf(2.0f * x);
  return 1.0f - 2.0f / (e + 1.0f);
}

#define BS_ 16640L  // 65*256, per-batch stride of buf_s

// ---------- convert reused weights fp32 -> bf16 into ws ----------
__global__ __launch_bounds__(256) void kprep(
    const float* __restrict__ a0, const float* __restrict__ a1,
    const float* __restrict__ a2, const float* __restrict__ a3,
    const float* __restrict__ a4, const float* __restrict__ a5,
    u16* __restrict__ dst)
{
  int i = blockIdx.x * 256 + threadIdx.x;
  const float* s; int o;
  if (i < 65536)        { s = a0; o = i; }
  else if (i < 851968)  { s = a1; o = i - 65536; }
  else if (i < 1114112) { s = a2; o = i - 851968; }
  else if (i < 1441792) { s = a3; o = i - 1114112; }
  else if (i < 1769472) { s = a4; o = i - 1441792; }
  else                  { s = a5; o = i - 1769472; }
  dst[i] = f2b(s[o]);
}

// ---------- init: zero th[0], head logits, barrier state ----------
__global__ __launch_bounds__(256) void kinit(u16* thb, float* lg1, unsigned* bar) {
  int i = blockIdx.x * 256 + threadIdx.x;
  if (i < 262144) thb[i] = 0;
  if (i < 193536) lg1[i] = 0.0f;
  if (i < 2) bar[i] = 0u;
}

// ---------- phase 1 (MFMA): buf = selu(embed[tok] @ W_in^T + b), outputs0 head ----------
__global__ __launch_bounds__(256) void kbuf2(
    const int* __restrict__ tokens, const float* __restrict__ embed,
    const u16* __restrict__ w_inB, const float* __restrict__ b_in,
    const float* __restrict__ w_out, const float* __restrict__ b_out,
    float* __restrict__ out0, u16* __restrict__ buf_s, u16* __restrict__ padv)
{
  __shared__ u16 Wl[128 * 264];   // 67.6 KB : half of W_in, [col][K] stride 264
  __shared__ u16 Bufl[64 * 264];  // 33.8 KB : selu outputs, [row][col]
  const int tid = threadIdx.x;
  const int wv = tid >> 6, ln = tid & 63, l15 = ln & 15, lq = ln >> 4;

  // gather A rows (fp32 -> bf16) into registers: row = wv*16 + l15
  int pos = blockIdx.x * 64 + wv * 16 + l15;
  int b = pos / 127, t = pos - b * 127;
  int tok = tokens[b * 127 + t];
  const float* arow = embed + (size_t)tok * 256 + lq * 8;
  short8 av[8];
#pragma unroll
  for (int kk = 0; kk < 8; ++kk) {
    float4 f0 = *(const float4*)(arow + kk * 32);
    float4 f1 = *(const float4*)(arow + kk * 32 + 4);
    U16x8 tmp;
    tmp.h[0] = f2b(f0.x); tmp.h[1] = f2b(f0.y); tmp.h[2] = f2b(f0.z); tmp.h[3] = f2b(f0.w);
    tmp.h[4] = f2b(f1.x); tmp.h[5] = f2b(f1.y); tmp.h[6] = f2b(f1.z); tmp.h[7] = f2b(f1.w);
    av[kk] = tmp.s;
  }

  const float SELU_A = 1.6732632423543772f, SELU_S = 1.0507009873554805f;
#pragma unroll 1
  for (int hf = 0; hf < 2; ++hf) {
    __syncthreads();
    {
      int col = tid >> 1, seg = tid & 1;
      const uint4* s = (const uint4*)(w_inB + (size_t)(hf * 128 + col) * 256 + seg * 128);
      uint4* d = (uint4*)(Wl + col * 264 + seg * 128);
#pragma unroll
      for (int i = 0; i < 16; ++i) d[i] = s[i];
    }
    __syncthreads();
#pragma unroll 1
    for (int t2 = 0; t2 < 8; ++t2) {
      f32x4 acc = {0.f, 0.f, 0.f, 0.f};
#pragma unroll
      for (int kk = 0; kk < 8; ++kk) {
        U16x8 bv; bv.u = *(const uint4*)(Wl + (t2 * 16 + l15) * 264 + kk * 32 + lq * 8);
        acc = __builtin_amdgcn_mfma_f32_16x16x32_bf16(av[kk], bv.s, acc, 0, 0, 0);
      }
      int col = hf * 128 + t2 * 16 + l15;
      float bi = b_in[col];
#pragma unroll
      for (int i = 0; i < 4; ++i) {
        float v = acc[i] + bi;
        v = (v > 0.0f) ? SELU_S * v : SELU_S * SELU_A * (__expf(v) - 1.0f);
        Bufl[(wv * 16 + lq * 4 + i) * 264 + col] = f2b(v);
      }
    }
  }
  __syncthreads();

  // coalesced write-out of buf slots (and pad vector)
  {
    int row = tid >> 2, seg = tid & 3;
    int pos2 = blockIdx.x * 64 + row;
    int b2 = pos2 / 127, t2p = pos2 - b2 * 127;
    u16* dst = 0;
    if (t2p <= 64) dst = buf_s + (size_t)b2 * BS_ + t2p * 256 + seg * 64;
    else if (t2p == 126 && b2 == 0) dst = padv + seg * 64;
    if (dst) {
      const uint4* s = (const uint4*)(Bufl + row * 264 + seg * 64);
      uint4* d = (uint4*)dst;
#pragma unroll
      for (int i = 0; i < 8; ++i) d[i] = s[i];
    }
  }
  // outputs0 head: wave wv handles rows wv*16 .. wv*16+15
#pragma unroll 1
  for (int pp = 0; pp < 16; ++pp) {
    int p = wv * 16 + pp;
    uint2 hu = *(const uint2*)(Bufl + p * 264 + ln * 4);
    const u16* hh = (const u16*)&hu;
    float lg[3];
#pragma unroll
    for (int o = 0; o < 3; ++o) {
      float4 wvv = *(const float4*)(w_out + o * 256 + ln * 4);
      lg[o] = b2f(hh[0]) * wvv.x + b2f(hh[1]) * wvv.y + b2f(hh[2]) * wvv.z + b2f(hh[3]) * wvv.w;
    }
#pragma unroll
    for (int o = 0; o < 3; ++o)
      for (int off = 32; off > 0; off >>= 1) lg[o] += __shfl_down(lg[o], off);
    if (ln == 0) {
      float l0 = lg[0] + b_out[0];
      float l1 = lg[1] + b_out[1];
      float l2 = lg[2] + b_out[2];
      float m = fmaxf(l0, fmaxf(l1, l2));
      float lse = m + __logf(__expf(l0 - m) + __expf(l1 - m) + __expf(l2 - m));
      int pos3 = blockIdx.x * 64 + p;
      int b3 = pos3 / 127, t3 = pos3 - b3 * 127;
      size_t o0 = ((size_t)t3 * 1024 + b3) * 3;
      out0[o0 + 0] = l0 - lse;
      out0[o0 + 1] = l1 - lse;
      out0[o0 + 2] = l2 - lse;
    }
  }
}

// ---------- grid barrier (monotonic count + generation flag) ----------
__device__ __forceinline__ void gridbar(unsigned* cnt, unsigned* gen, unsigned k) {
  __syncthreads();
  if (threadIdx.x == 0) {
    unsigned prev = __hip_atomic_fetch_add(cnt, 1u, __ATOMIC_RELEASE, __HIP_MEMORY_SCOPE_AGENT);
    if (prev == k * 256u - 1u)
      __hip_atomic_store(gen, k, __ATOMIC_RELEASE, __HIP_MEMORY_SCOPE_AGENT);
    unsigned guard = 0;
    while (__hip_atomic_load(gen, __ATOMIC_RELAXED, __HIP_MEMORY_SCOPE_AGENT) < k) {
      __builtin_amdgcn_s_sleep(2);
      if (++guard > (1u << 27)) break;  // escape hatch: fail visibly, never hang
    }
    __threadfence();
  }
  __syncthreads();
}

struct SeqArgs {
  const u16* buf_s; const u16* padv; u16* hR; u16* thb;
  const u16* w_ihB; const u16* w_hhB;
  const u16* w_lB; const u16* w_rB; const u16* w_tB;
  const float* b_ih; const float* b_hh; const float* b_l;
  const float* w_out;
  float* lg1;
  unsigned* barcnt; unsigned* bargen;
};

// ---------- persistent sequential phase: 127 tracker + 63 reduce steps ----------
__global__ __launch_bounds__(256) void kseq(SeqArgs A) {
  __shared__ u16 Wt[64 * 1048];  // 134 KB tracker W slice, resident all steps
  const int tid = threadIdx.x;
  const int bid = blockIdx.x;
  const int m = bid & 15, n = bid >> 4;
  {
    int col = tid >> 2, kseg = (tid & 3) * 256;
    int nr = (col >> 4) * 256 + n * 16 + (col & 15);
    const uint4* s = (const uint4*)((kseg < 768) ? (A.w_ihB + (size_t)nr * 768 + kseg)
                                                 : (A.w_hhB + (size_t)nr * 256));
    uint4* d = (uint4*)(Wt + col * 1048 + kseg);
#pragma unroll 8
    for (int i = 0; i < 32; ++i) d[i] = s[i];
  }
  const int wv = tid >> 6, ln = tid & 63, l15 = ln & 15, lq = ln >> 4;
  const long grow = m * 64 + wv * 16 + l15;
  const int c = n * 16 + l15;
  const int erow0 = m * 64 + wv * 16 + lq * 4;
  float bt[4], br[5], wo[3];
#pragma unroll
  for (int q = 0; q < 4; ++q) bt[q] = A.b_ih[q * 256 + c] + A.b_hh[q * 256 + c];
#pragma unroll
  for (int q = 0; q < 5; ++q) br[q] = A.b_l[q * 256 + c];
#pragma unroll
  for (int o = 0; o < 3; ++o) wo[o] = A.w_out[o * 256 + c];
  float tcv[4] = {0.f, 0.f, 0.f, 0.f};
  float rcv[4] = {0.f, 0.f, 0.f, 0.f};
  __syncthreads();

  const u16* bufs = A.buf_s;
  unsigned bk = 0;
#pragma unroll 1
  for (int t = 0; t < 127; ++t) {
    // ---- schedule (static) ----
    const u16 *A1, *A2; long S1, S2; int k; bool isR = false;
    if (t == 0)      { k = 0;  A1 = A.padv; S1 = 0;   A2 = A.padv; S2 = 0; }
    else if (t == 1) { k = 1;  A1 = bufs;            S1 = BS_; A2 = A.padv; S2 = 0; }
    else if (t == 2) { k = 2;  A1 = bufs + 256;      S1 = BS_; A2 = bufs;       S2 = BS_; }
    else if (t == 3) { k = 3;  A1 = bufs + 512;      S1 = BS_; A2 = bufs + 256; S2 = BS_; isR = true; }
    else if (t == 126) { k = 64; A1 = A.hR + (62 & 1) * 262144; S1 = 256; A2 = bufs; S2 = BS_; isR = true; }
    else if ((t & 1) == 0) { int i = (t - 2) / 2; k = i + 2; A1 = A.hR + (size_t)(i & 1) * 262144; S1 = 256; A2 = bufs; S2 = BS_; }
    else { int i = (t - 3) / 2; k = i + 3; A1 = bufs + (i + 2) * 256; S1 = BS_; A2 = A.hR + (size_t)(i & 1) * 262144; S2 = 256; isR = true; }

    const u16* thin = A.thb + (size_t)(t & 1) * 262144;
    u16* thout = A.thb + (size_t)((t + 1) & 1) * 262144;

    // ---- tracker MFMA ----
    f32x4 acc[4] = { {0.f,0.f,0.f,0.f}, {0.f,0.f,0.f,0.f}, {0.f,0.f,0.f,0.f}, {0.f,0.f,0.f,0.f} };
    {
      const u16* ap[4] = { bufs + k * 256 + grow * BS_, A1 + grow * S1,
                           A2 + grow * S2, thin + grow * 256 };
#pragma unroll 1
      for (int ch = 0; ch < 4; ++ch) {
        const u16* a = ap[ch] + 8 * lq;
#pragma unroll
        for (int kk = 0; kk < 8; ++kk) {
          U16x8 avv; avv.u = *(const uint4*)(a + kk * 32);
#pragma unroll
          for (int qt = 0; qt < 4; ++qt) {
            U16x8 bv; bv.u = *(const uint4*)(Wt + (qt * 16 + l15) * 1048 + ch * 256 + kk * 32 + 8 * lq);
            acc[qt] = __builtin_amdgcn_mfma_f32_16x16x32_bf16(avv.s, bv.s, acc[qt], 0, 0, 0);
          }
        }
      }
    }
#pragma unroll
    for (int i = 0; i < 4; ++i) {
      float gi = acc[0][i] + bt[0];
      float gf = acc[1][i] + bt[1];
      float gg = acc[2][i] + bt[2];
      float go = acc[3][i] + bt[3];
      float tcn = sig_(gf) * tcv[i] + sig_(gi) * tanh_(gg);
      tcv[i] = tcn;
      thout[(size_t)(erow0 + i) * 256 + c] = f2b(sig_(go) * tanh_(tcn));
    }
    ++bk; gridbar(A.barcnt, A.bargen, bk);

    if (isR) {
      int j; const u16 *lH, *rH; long lHs, rHs; int lcase; const u16 *lCg = 0, *rCg = 0;
      if (t == 3) { j = 1; lH = bufs + 256; lHs = BS_; rH = bufs + 512; rHs = BS_;
                    lcase = 0; lCg = bufs + 256; rCg = bufs + 512; }
      else if (t == 126) { j = 63; lH = bufs; lHs = BS_; rH = A.hR + (62 & 1) * 262144; rHs = 256;
                    lcase = 2; lCg = bufs; }
      else { int i2 = (t - 3) / 2; j = i2 + 1; lH = A.hR + (size_t)(i2 & 1) * 262144; lHs = 256;
             rH = bufs + (i2 + 2) * 256; rHs = BS_; lcase = 1; rCg = bufs + (i2 + 2) * 256; }

      f32x4 acc2[5] = { {0.f,0.f,0.f,0.f}, {0.f,0.f,0.f,0.f}, {0.f,0.f,0.f,0.f},
                        {0.f,0.f,0.f,0.f}, {0.f,0.f,0.f,0.f} };
      {
        const u16* ap[3] = { lH + grow * lHs, rH + grow * rHs, thout + grow * 256 };
        const u16* wch[3] = { A.w_lB, A.w_rB, A.w_tB };
#pragma unroll 1
        for (int ch = 0; ch < 3; ++ch) {
          const u16* a = ap[ch] + 8 * lq;
          const u16* wb = wch[ch];
#pragma unroll
          for (int kk = 0; kk < 8; ++kk) {
            U16x8 avv; avv.u = *(const uint4*)(a + kk * 32);
#pragma unroll
            for (int ct = 0; ct < 5; ++ct) {
              U16x8 bv; bv.u = *(const uint4*)(wb + (size_t)(ct * 256 + c) * 256 + kk * 32 + 8 * lq);
              acc2[ct] = __builtin_amdgcn_mfma_f32_16x16x32_bf16(avv.s, bv.s, acc2[ct], 0, 0, 0);
            }
          }
        }
      }
      u16* oH = A.hR + (size_t)(j & 1) * 262144;
      float hv4[4];
#pragma unroll
      for (int i = 0; i < 4; ++i) {
        int row = erow0 + i;
        float a_ = acc2[0][i] + br[0];
        float ig = acc2[1][i] + br[1];
        float f1 = acc2[2][i] + br[2];
        float f2g = acc2[3][i] + br[3];
        float og = acc2[4][i] + br[4];
        float lc = (lcase == 1) ? rcv[i] : b2f(lCg[(size_t)row * BS_ + c]);
        float rc = (lcase == 2) ? rcv[i] : b2f(rCg[(size_t)row * BS_ + c]);
        float cn = tanh_(a_) * sig_(ig) + sig_(f1) * lc + sig_(f2g) * rc;
        float hn = sig_(og) * tanh_(cn);
        rcv[i] = cn;
        oH[(size_t)row * 256 + c] = f2b(hn);
        hv4[i] = hn;
      }
      float pr[12];
#pragma unroll
      for (int o = 0; o < 3; ++o)
#pragma unroll
        for (int i = 0; i < 4; ++i) pr[o * 4 + i] = hv4[i] * wo[o];
#pragma unroll
      for (int u = 0; u < 12; ++u)
#pragma unroll
        for (int mm = 1; mm < 16; mm <<= 1) pr[u] += __shfl_xor(pr[u], mm);
      if (l15 == 0) {
        float* lgo = A.lg1 + (size_t)(j - 1) * 3072;
#pragma unroll
        for (int o = 0; o < 3; ++o)
#pragma unroll
          for (int i = 0; i < 4; ++i)
            atomicAdd(lgo + (size_t)(erow0 + i) * 3 + o, pr[o * 4 + i]);
      }
      ++bk; gridbar(A.barcnt, A.bargen, bk);
    }
  }
}

// ---------- finalize outs1: log-softmax of accumulated logits ----------
__global__ __launch_bounds__(256) void kfin(const float* __restrict__ lg1,
    const float* __restrict__ b_out, float* __restrict__ out1)
{
  int r = blockIdx.x * 256 + threadIdx.x;
  if (r >= 64512) return;
  float l0 = lg1[r * 3 + 0] + b_out[0];
  float l1 = lg1[r * 3 + 1] + b_out[1];
  float l2 = lg1[r * 3 + 2] + b_out[2];
  float m = fmaxf(l0, fmaxf(l1, l2));
  float lse = m + __logf(__expf(l0 - m) + __expf(l1 - m) + __expf(l2 - m));
  out1[r * 3 + 0] = l0 - lse;
  out1[r * 3 + 1] = l1 - lse;
  out1[r * 3 + 2] = l2 - lse;
}

extern "C" void kernel_launch(void* const* d_in, const int* in_sizes, int n_in,
                              void* d_out, int out_size, void* d_ws, size_t ws_size,
                              hipStream_t stream) {
  const int* tokens   = (const int*)d_in[0];
  const float* embed  = (const float*)d_in[2];
  const float* w_in   = (const float*)d_in[3];
  const float* b_in   = (const float*)d_in[4];
  const float* left_w = (const float*)d_in[5];
  const float* left_b = (const float*)d_in[6];
  const float* right_w= (const float*)d_in[7];
  const float* track_w= (const float*)d_in[8];
  const float* w_ih   = (const float*)d_in[9];
  const float* w_hh   = (const float*)d_in[10];
  const float* b_ih   = (const float*)d_in[11];
  const float* b_hh   = (const float*)d_in[12];
  const float* w_out  = (const float*)d_in[13];
  const float* b_out  = (const float*)d_in[14];
  float* out = (float*)d_out;

  char* ws = (char*)d_ws;
  u16* wB    = (u16*)ws;                    // bf16 weight pool
  u16* w_inB = wB;
  u16* w_ihB = wB + 65536;
  u16* w_hhB = wB + 851968;
  u16* w_lB  = wB + 1114112;
  u16* w_rB  = wB + 1441792;
  u16* w_tB  = wB + 1769472;
  u16* buf_s = (u16*)(ws + 4194304);        // [1024][65][256] bf16
  u16* padv  = (u16*)(ws + 38273024);       // [256] bf16
  u16* hR    = (u16*)(ws + 38273536);       // [2][1024][256] bf16
  unsigned* bar = (unsigned*)(ws + 41419264); // {cnt, gen}
  u16* thb   = (u16*)(ws + 42467840);       // [2][1024][256] bf16
  float* lg1 = (float*)(ws + 43516416);     // [63][1024][3] f32

  kprep<<<8192, 256, 0, stream>>>(w_in, w_ih, w_hh, left_w, right_w, track_w, wB);
  kinit<<<1024, 256, 0, stream>>>(thb, lg1, bar);
  kbuf2<<<2032, 256, 0, stream>>>(tokens, embed, w_inB, b_in, w_out, b_out, out, buf_s, padv);

  SeqArgs sa;
  sa.buf_s = buf_s; sa.padv = padv; sa.hR = hR; sa.thb = thb;
  sa.w_ihB = w_ihB; sa.w_hhB = w_hhB;
  sa.w_lB = w_lB; sa.w_rB = w_rB; sa.w_tB = w_tB;
  sa.b_ih = b_ih; sa.b_hh = b_hh; sa.b_l = left_b;
  sa.w_out = w_out; sa.lg1 = lg1;
  sa.barcnt = bar; sa.bargen = bar + 1;
  void* kargs[] = { &sa };
  hipLaunchCooperativeKernel((const void*)kseq, dim3(256), dim3(256), kargs, 0, stream);

  kfin<<<252, 256, 0, stream>>>(lg1, b_out, out + 390144);
}

// Round 4
// 3035.919 us; speedup vs baseline: 1.6782x; 1.6782x over previous
//
#include <hip/hip_runtime.h>

typedef unsigned short u16;
typedef __attribute__((ext_vector_type(8))) short short8;
typedef __attribute__((ext_vector_type(4))) float f32x4;

union U16x8 { uint4 u; short8 s; u16 h[8]; };
struct Frag8 { uint4 v[8]; };

__device__ __forceinline__ float b2f(u16 u) {
  union { unsigned int i; float f; } x; x.i = ((unsigned int)u) << 16; return x.f;
}
__device__ __forceinline__ u16 f2b(float f) {
  union { float f; unsigned int i; } x; x.f = f;
  unsigned int r = x.i + 0x7FFFu + ((x.i >> 16) & 1u);
  return (u16)(r >> 16);
}
__device__ __forceinline__ float sig_(float x) { return 1.0f / (1.0f + __expf(-x)); }
__device__ __forceinline__ float tanh_(float x) {
  float e = __expf(2.0f * x);
  return 1.0f - 2.0f / (e + 1.0f);
}

#define BS_ 16640L  // 65*256, per-batch stride of buf_s

// ---- coherent (L2-bypass, L3-visible) helpers ----
__device__ __forceinline__ void plain8(Frag8& f, const u16* p) {
#pragma unroll
  for (int kk = 0; kk < 8; ++kk) f.v[kk] = *(const uint4*)(p + kk * 32);
}
__device__ __forceinline__ void ldc8(Frag8& f, const u16* p) {
  asm volatile(
      "global_load_dwordx4 %0, %8, off sc0 sc1\n\t"
      "global_load_dwordx4 %1, %8, off offset:64 sc0 sc1\n\t"
      "global_load_dwordx4 %2, %8, off offset:128 sc0 sc1\n\t"
      "global_load_dwordx4 %3, %8, off offset:192 sc0 sc1\n\t"
      "global_load_dwordx4 %4, %8, off offset:256 sc0 sc1\n\t"
      "global_load_dwordx4 %5, %8, off offset:320 sc0 sc1\n\t"
      "global_load_dwordx4 %6, %8, off offset:384 sc0 sc1\n\t"
      "global_load_dwordx4 %7, %8, off offset:448 sc0 sc1\n\t"
      "s_waitcnt vmcnt(0)"
      : "=&v"(f.v[0]), "=&v"(f.v[1]), "=&v"(f.v[2]), "=&v"(f.v[3]),
        "=&v"(f.v[4]), "=&v"(f.v[5]), "=&v"(f.v[6]), "=&v"(f.v[7])
      : "v"(p) : "memory");
}
__device__ __forceinline__ void ldc16(Frag8& f, const u16* p, Frag8& g, const u16* q) {
  asm volatile(
      "global_load_dwordx4 %0, %16, off sc0 sc1\n\t"
      "global_load_dwordx4 %1, %16, off offset:64 sc0 sc1\n\t"
      "global_load_dwordx4 %2, %16, off offset:128 sc0 sc1\n\t"
      "global_load_dwordx4 %3, %16, off offset:192 sc0 sc1\n\t"
      "global_load_dwordx4 %4, %16, off offset:256 sc0 sc1\n\t"
      "global_load_dwordx4 %5, %16, off offset:320 sc0 sc1\n\t"
      "global_load_dwordx4 %6, %16, off offset:384 sc0 sc1\n\t"
      "global_load_dwordx4 %7, %16, off offset:448 sc0 sc1\n\t"
      "global_load_dwordx4 %8, %17, off sc0 sc1\n\t"
      "global_load_dwordx4 %9, %17, off offset:64 sc0 sc1\n\t"
      "global_load_dwordx4 %10, %17, off offset:128 sc0 sc1\n\t"
      "global_load_dwordx4 %11, %17, off offset:192 sc0 sc1\n\t"
      "global_load_dwordx4 %12, %17, off offset:256 sc0 sc1\n\t"
      "global_load_dwordx4 %13, %17, off offset:320 sc0 sc1\n\t"
      "global_load_dwordx4 %14, %17, off offset:384 sc0 sc1\n\t"
      "global_load_dwordx4 %15, %17, off offset:448 sc0 sc1\n\t"
      "s_waitcnt vmcnt(0)"
      : "=&v"(f.v[0]), "=&v"(f.v[1]), "=&v"(f.v[2]), "=&v"(f.v[3]),
        "=&v"(f.v[4]), "=&v"(f.v[5]), "=&v"(f.v[6]), "=&v"(f.v[7]),
        "=&v"(g.v[0]), "=&v"(g.v[1]), "=&v"(g.v[2]), "=&v"(g.v[3]),
        "=&v"(g.v[4]), "=&v"(g.v[5]), "=&v"(g.v[6]), "=&v"(g.v[7])
      : "v"(p), "v"(q) : "memory");
}
__device__ __forceinline__ void stc16(u16* p, u16 v) {
  unsigned vv = v;
  asm volatile("global_store_short %0, %1, off sc0 sc1" :: "v"(p), "v"(vv) : "memory");
}

// ---------- convert reused weights fp32 -> bf16 into ws ----------
__global__ __launch_bounds__(256) void kprep(
    const float* __restrict__ a0, const float* __restrict__ a1,
    const float* __restrict__ a2, const float* __restrict__ a3,
    const float* __restrict__ a4, const float* __restrict__ a5,
    u16* __restrict__ dst)
{
  int i = blockIdx.x * 256 + threadIdx.x;
  const float* s; int o;
  if (i < 65536)        { s = a0; o = i; }
  else if (i < 851968)  { s = a1; o = i - 65536; }
  else if (i < 1114112) { s = a2; o = i - 851968; }
  else if (i < 1441792) { s = a3; o = i - 1114112; }
  else if (i < 1769472) { s = a4; o = i - 1441792; }
  else                  { s = a5; o = i - 1769472; }
  dst[i] = f2b(s[o]);
}

// ---------- init: zero head logits + per-group barrier state ----------
__global__ __launch_bounds__(256) void kinit(float* lg1, unsigned* bar) {
  int i = blockIdx.x * 256 + threadIdx.x;
  if (i < 193536) lg1[i] = 0.0f;
  if (i < 1024) bar[i] = 0u;
}

// ---------- phase 1 (MFMA): buf = selu(embed[tok] @ W_in^T + b), outputs0 head ----------
__global__ __launch_bounds__(256) void kbuf2(
    const int* __restrict__ tokens, const float* __restrict__ embed,
    const u16* __restrict__ w_inB, const float* __restrict__ b_in,
    const float* __restrict__ w_out, const float* __restrict__ b_out,
    float* __restrict__ out0, u16* __restrict__ buf_s, u16* __restrict__ padv)
{
  __shared__ u16 Wl[128 * 264];
  __shared__ u16 Bufl[64 * 264];
  const int tid = threadIdx.x;
  const int wv = tid >> 6, ln = tid & 63, l15 = ln & 15, lq = ln >> 4;

  int pos = blockIdx.x * 64 + wv * 16 + l15;
  int b = pos / 127, t = pos - b * 127;
  int tok = tokens[b * 127 + t];
  const float* arow = embed + (size_t)tok * 256 + lq * 8;
  short8 av[8];
#pragma unroll
  for (int kk = 0; kk < 8; ++kk) {
    float4 f0 = *(const float4*)(arow + kk * 32);
    float4 f1 = *(const float4*)(arow + kk * 32 + 4);
    U16x8 tmp;
    tmp.h[0] = f2b(f0.x); tmp.h[1] = f2b(f0.y); tmp.h[2] = f2b(f0.z); tmp.h[3] = f2b(f0.w);
    tmp.h[4] = f2b(f1.x); tmp.h[5] = f2b(f1.y); tmp.h[6] = f2b(f1.z); tmp.h[7] = f2b(f1.w);
    av[kk] = tmp.s;
  }

  const float SELU_A = 1.6732632423543772f, SELU_S = 1.0507009873554805f;
#pragma unroll 1
  for (int hf = 0; hf < 2; ++hf) {
    __syncthreads();
    {
      int col = tid >> 1, seg = tid & 1;
      const uint4* s = (const uint4*)(w_inB + (size_t)(hf * 128 + col) * 256 + seg * 128);
      uint4* d = (uint4*)(Wl + col * 264 + seg * 128);
#pragma unroll
      for (int i = 0; i < 16; ++i) d[i] = s[i];
    }
    __syncthreads();
#pragma unroll 1
    for (int t2 = 0; t2 < 8; ++t2) {
      f32x4 acc = {0.f, 0.f, 0.f, 0.f};
#pragma unroll
      for (int kk = 0; kk < 8; ++kk) {
        U16x8 bv; bv.u = *(const uint4*)(Wl + (t2 * 16 + l15) * 264 + kk * 32 + lq * 8);
        acc = __builtin_amdgcn_mfma_f32_16x16x32_bf16(av[kk], bv.s, acc, 0, 0, 0);
      }
      int col = hf * 128 + t2 * 16 + l15;
      float bi = b_in[col];
#pragma unroll
      for (int i = 0; i < 4; ++i) {
        float v = acc[i] + bi;
        v = (v > 0.0f) ? SELU_S * v : SELU_S * SELU_A * (__expf(v) - 1.0f);
        Bufl[(wv * 16 + lq * 4 + i) * 264 + col] = f2b(v);
      }
    }
  }
  __syncthreads();

  {
    int row = tid >> 2, seg = tid & 3;
    int pos2 = blockIdx.x * 64 + row;
    int b2 = pos2 / 127, t2p = pos2 - b2 * 127;
    u16* dst = 0;
    if (t2p <= 64) dst = buf_s + (size_t)b2 * BS_ + t2p * 256 + seg * 64;
    else if (t2p == 126 && b2 == 0) dst = padv + seg * 64;
    if (dst) {
      const uint4* s = (const uint4*)(Bufl + row * 264 + seg * 64);
      uint4* d = (uint4*)dst;
#pragma unroll
      for (int i = 0; i < 8; ++i) d[i] = s[i];
    }
  }
#pragma unroll 1
  for (int pp = 0; pp < 16; ++pp) {
    int p = wv * 16 + pp;
    uint2 hu = *(const uint2*)(Bufl + p * 264 + ln * 4);
    const u16* hh = (const u16*)&hu;
    float lg[3];
#pragma unroll
    for (int o = 0; o < 3; ++o) {
      float4 wvv = *(const float4*)(w_out + o * 256 + ln * 4);
      lg[o] = b2f(hh[0]) * wvv.x + b2f(hh[1]) * wvv.y + b2f(hh[2]) * wvv.z + b2f(hh[3]) * wvv.w;
    }
#pragma unroll
    for (int o = 0; o < 3; ++o)
      for (int off = 32; off > 0; off >>= 1) lg[o] += __shfl_down(lg[o], off);
    if (ln == 0) {
      float l0 = lg[0] + b_out[0];
      float l1 = lg[1] + b_out[1];
      float l2 = lg[2] + b_out[2];
      float m = fmaxf(l0, fmaxf(l1, l2));
      float lse = m + __logf(__expf(l0 - m) + __expf(l1 - m) + __expf(l2 - m));
      int pos3 = blockIdx.x * 64 + p;
      int b3 = pos3 / 127, t3 = pos3 - b3 * 127;
      size_t o0 = ((size_t)t3 * 1024 + b3) * 3;
      out0[o0 + 0] = l0 - lse;
      out0[o0 + 1] = l1 - lse;
      out0[o0 + 2] = l2 - lse;
    }
  }
}

// ---------- per-group (16-block) barrier: relaxed atomics at L3, no cache flush ----------
__device__ __forceinline__ void groupbar(unsigned* cnt, unsigned* gen, unsigned k) {
  asm volatile("s_waitcnt vmcnt(0)" ::: "memory");  // drain this wave's sc1 stores
  __syncthreads();                                   // all waves drained (barrier waits mem ops)
  if (threadIdx.x == 0) {
    unsigned prev, one = 1u;
    asm volatile("global_atomic_add %0, %1, %2, off sc0 sc1\n\ts_waitcnt vmcnt(0)"
                 : "=&v"(prev) : "v"(cnt), "v"(one) : "memory");
    if (prev == k * 16u - 1u) {
      asm volatile("global_store_dword %0, %1, off sc0 sc1" :: "v"(gen), "v"(k) : "memory");
    }
    unsigned g = 0, guard = 0;
    for (;;) {
      asm volatile("global_load_dword %0, %1, off sc0 sc1\n\ts_waitcnt vmcnt(0)"
                   : "=&v"(g) : "v"(gen) : "memory");
      if (g >= k) break;
      __builtin_amdgcn_s_sleep(4);
      if (++guard > (1u << 20)) break;  // escape hatch: fail visibly, never hang
    }
  }
  __syncthreads();
}

struct SeqArgs {
  const u16* buf_s; const u16* padv; u16* hR; u16* thb;
  const u16* w_ihB; const u16* w_hhB;
  const u16* w_lB; const u16* w_rB; const u16* w_tB;
  const float* b_ih; const float* b_hh; const float* b_l;
  const float* w_out;
  float* lg1;
  unsigned* bar;
};

// ---------- persistent sequential phase: 127 tracker + 63 reduce steps ----------
__global__ __launch_bounds__(256, 1) void kseq(SeqArgs A) {
  __shared__ u16 Wt[64 * 1048];  // tracker W slice, resident all steps
  const int tid = threadIdx.x;
  const int bid = blockIdx.x;
  const int m = bid & 15, n = bid >> 4;  // group = m (16 col-blocks per row-group)
  {
    int col = tid >> 2, kseg = (tid & 3) * 256;
    int nr = (col >> 4) * 256 + n * 16 + (col & 15);
    const uint4* s = (const uint4*)((kseg < 768) ? (A.w_ihB + (size_t)nr * 768 + kseg)
                                                 : (A.w_hhB + (size_t)nr * 256));
    uint4* d = (uint4*)(Wt + col * 1048 + kseg);
#pragma unroll 8
    for (int i = 0; i < 32; ++i) d[i] = s[i];
  }
  const int wv = tid >> 6, ln = tid & 63, l15 = ln & 15, lq = ln >> 4;
  const long grow = (long)m * 64 + wv * 16 + l15;
  const int c = n * 16 + l15;
  const int erow0 = m * 64 + wv * 16 + lq * 4;
  unsigned* bcnt = A.bar + m * 64;
  unsigned* bgen = A.bar + m * 64 + 16;
  float bt[4], br[5], wo[3];
#pragma unroll
  for (int q = 0; q < 4; ++q) bt[q] = A.b_ih[q * 256 + c] + A.b_hh[q * 256 + c];
#pragma unroll
  for (int q = 0; q < 5; ++q) br[q] = A.b_l[q * 256 + c];
#pragma unroll
  for (int o = 0; o < 3; ++o) wo[o] = A.w_out[o * 256 + c];
  float tcv[4] = {0.f, 0.f, 0.f, 0.f};
  float rcv[4] = {0.f, 0.f, 0.f, 0.f};
  __syncthreads();

  const u16* bufs = A.buf_s;
  unsigned bk = 0;
#pragma unroll 1
  for (int t = 0; t < 127; ++t) {
    // ---- static schedule ----
    const u16 *A1, *A2; long S1, S2; int k; bool isR = false, c1 = false, c2 = false;
    if (t == 0)      { k = 0;  A1 = A.padv; S1 = 0;   A2 = A.padv; S2 = 0; }
    else if (t == 1) { k = 1;  A1 = bufs;            S1 = BS_; A2 = A.padv; S2 = 0; }
    else if (t == 2) { k = 2;  A1 = bufs + 256;      S1 = BS_; A2 = bufs;       S2 = BS_; }
    else if (t == 3) { k = 3;  A1 = bufs + 512;      S1 = BS_; A2 = bufs + 256; S2 = BS_; isR = true; }
    else if (t == 126) { k = 64; A1 = A.hR + (62 & 1) * 262144; S1 = 256; c1 = true; A2 = bufs; S2 = BS_; isR = true; }
    else if ((t & 1) == 0) { int i = (t - 2) / 2; k = i + 2; A1 = A.hR + (size_t)(i & 1) * 262144; S1 = 256; c1 = true; A2 = bufs; S2 = BS_; }
    else { int i = (t - 3) / 2; k = i + 3; A1 = bufs + (i + 2) * 256; S1 = BS_; A2 = A.hR + (size_t)(i & 1) * 262144; S2 = 256; c2 = true; isR = true; }

    const u16* thin = A.thb + (size_t)(t & 1) * 262144;
    u16* thout = A.thb + (size_t)((t + 1) & 1) * 262144;

    // ---- gather all 4 A-channel fragments ----
    Frag8 f0, f1, f2, f3;
    plain8(f0, bufs + k * 256 + grow * BS_ + 8 * lq);
    const u16* a1p = A1 + grow * S1 + 8 * lq;
    const u16* a2p = A2 + grow * S2 + 8 * lq;
    const u16* a3p = thin + grow * 256 + 8 * lq;
    if (t == 0) {
      plain8(f1, a1p); plain8(f2, a2p);
#pragma unroll
      for (int kk = 0; kk < 8; ++kk) f3.v[kk] = make_uint4(0, 0, 0, 0);
    } else if (c1) {
      plain8(f2, a2p); ldc16(f3, a3p, f1, a1p);
    } else if (c2) {
      plain8(f1, a1p); ldc16(f3, a3p, f2, a2p);
    } else {
      plain8(f1, a1p); plain8(f2, a2p); ldc8(f3, a3p);
    }

    // ---- tracker MFMA ----
    f32x4 acc[4] = { {0.f,0.f,0.f,0.f}, {0.f,0.f,0.f,0.f}, {0.f,0.f,0.f,0.f}, {0.f,0.f,0.f,0.f} };
    const Frag8* fs[4] = { &f0, &f1, &f2, &f3 };
#pragma unroll
    for (int ch = 0; ch < 4; ++ch) {
#pragma unroll
      for (int kk = 0; kk < 8; ++kk) {
        U16x8 avv; avv.u = fs[ch]->v[kk];
#pragma unroll
        for (int qt = 0; qt < 4; ++qt) {
          U16x8 bv; bv.u = *(const uint4*)(Wt + (qt * 16 + l15) * 1048 + ch * 256 + kk * 32 + 8 * lq);
          acc[qt] = __builtin_amdgcn_mfma_f32_16x16x32_bf16(avv.s, bv.s, acc[qt], 0, 0, 0);
        }
      }
    }
#pragma unroll
    for (int i = 0; i < 4; ++i) {
      float gi = acc[0][i] + bt[0];
      float gf = acc[1][i] + bt[1];
      float gg = acc[2][i] + bt[2];
      float go = acc[3][i] + bt[3];
      float tcn = sig_(gf) * tcv[i] + sig_(gi) * tanh_(gg);
      tcv[i] = tcn;
      stc16(thout + (size_t)(erow0 + i) * 256 + c, f2b(sig_(go) * tanh_(tcn)));
    }
    ++bk; groupbar(bcnt, bgen, bk);

    if (isR) {
      int j; const u16 *lH, *rH; long lHs, rHs; int lcase; const u16 *lCg = 0, *rCg = 0;
      if (t == 3) { j = 1; lH = bufs + 256; lHs = BS_; rH = bufs + 512; rHs = BS_;
                    lcase = 0; lCg = bufs + 256; rCg = bufs + 512; }
      else if (t == 126) { j = 63; lH = bufs; lHs = BS_; rH = A.hR + (62 & 1) * 262144; rHs = 256;
                    lcase = 2; lCg = bufs; }
      else { int i2 = (t - 3) / 2; j = i2 + 1; lH = A.hR + (size_t)(i2 & 1) * 262144; lHs = 256;
             rH = bufs + (i2 + 2) * 256; rHs = BS_; lcase = 1; rCg = bufs + (i2 + 2) * 256; }

      Frag8 fL, fR, fT;
      const u16* lp = lH + grow * lHs + 8 * lq;
      const u16* rp = rH + grow * rHs + 8 * lq;
      const u16* tp = thout + grow * 256 + 8 * lq;
      if (lcase == 0)      { plain8(fL, lp); plain8(fR, rp); ldc8(fT, tp); }
      else if (lcase == 2) { plain8(fL, lp); ldc16(fT, tp, fR, rp); }
      else                 { plain8(fR, rp); ldc16(fT, tp, fL, lp); }

      f32x4 acc2[5] = { {0.f,0.f,0.f,0.f}, {0.f,0.f,0.f,0.f}, {0.f,0.f,0.f,0.f},
                        {0.f,0.f,0.f,0.f}, {0.f,0.f,0.f,0.f} };
      const Frag8* fr[3] = { &fL, &fR, &fT };
      const u16* wch[3] = { A.w_lB, A.w_rB, A.w_tB };
#pragma unroll
      for (int ch = 0; ch < 3; ++ch) {
        const u16* wb = wch[ch];
#pragma unroll
        for (int kk = 0; kk < 8; ++kk) {
          U16x8 avv; avv.u = fr[ch]->v[kk];
#pragma unroll
          for (int ct = 0; ct < 5; ++ct) {
            U16x8 bv; bv.u = *(const uint4*)(wb + (size_t)(ct * 256 + c) * 256 + kk * 32 + 8 * lq);
            acc2[ct] = __builtin_amdgcn_mfma_f32_16x16x32_bf16(avv.s, bv.s, acc2[ct], 0, 0, 0);
          }
        }
      }
      u16* oH = A.hR + (size_t)(j & 1) * 262144;
      float hv4[4];
#pragma unroll
      for (int i = 0; i < 4; ++i) {
        int row = erow0 + i;
        float a_ = acc2[0][i] + br[0];
        float ig = acc2[1][i] + br[1];
        float f1g = acc2[2][i] + br[2];
        float f2g = acc2[3][i] + br[3];
        float og = acc2[4][i] + br[4];
        float lc = (lcase == 1) ? rcv[i] : b2f(lCg[(size_t)row * BS_ + c]);
        float rc = (lcase == 2) ? rcv[i] : b2f(rCg[(size_t)row * BS_ + c]);
        float cn = tanh_(a_) * sig_(ig) + sig_(f1g) * lc + sig_(f2g) * rc;
        float hn = sig_(og) * tanh_(cn);
        rcv[i] = cn;
        stc16(oH + (size_t)row * 256 + c, f2b(hn));
        hv4[i] = hn;
      }
      float pr[12];
#pragma unroll
      for (int o = 0; o < 3; ++o)
#pragma unroll
        for (int i = 0; i < 4; ++i) pr[o * 4 + i] = hv4[i] * wo[o];
#pragma unroll
      for (int u = 0; u < 12; ++u)
#pragma unroll
        for (int mm = 1; mm < 16; mm <<= 1) pr[u] += __shfl_xor(pr[u], mm);
      if (l15 == 0) {
        float* lgo = A.lg1 + (size_t)(j - 1) * 3072;
#pragma unroll
        for (int o = 0; o < 3; ++o)
#pragma unroll
          for (int i = 0; i < 4; ++i)
            atomicAdd(lgo + (size_t)(erow0 + i) * 3 + o, pr[o * 4 + i]);
      }
      ++bk; groupbar(bcnt, bgen, bk);
    }
  }
}

// ---------- finalize outs1: log-softmax of accumulated logits ----------
__global__ __launch_bounds__(256) void kfin(const float* __restrict__ lg1,
    const float* __restrict__ b_out, float* __restrict__ out1)
{
  int r = blockIdx.x * 256 + threadIdx.x;
  if (r >= 64512) return;
  float l0 = lg1[r * 3 + 0] + b_out[0];
  float l1 = lg1[r * 3 + 1] + b_out[1];
  float l2 = lg1[r * 3 + 2] + b_out[2];
  float m = fmaxf(l0, fmaxf(l1, l2));
  float lse = m + __logf(__expf(l0 - m) + __expf(l1 - m) + __expf(l2 - m));
  out1[r * 3 + 0] = l0 - lse;
  out1[r * 3 + 1] = l1 - lse;
  out1[r * 3 + 2] = l2 - lse;
}

extern "C" void kernel_launch(void* const* d_in, const int* in_sizes, int n_in,
                              void* d_out, int out_size, void* d_ws, size_t ws_size,
                              hipStream_t stream) {
  const int* tokens   = (const int*)d_in[0];
  const float* embed  = (const float*)d_in[2];
  const float* w_in   = (const float*)d_in[3];
  const float* b_in   = (const float*)d_in[4];
  const float* left_w = (const float*)d_in[5];
  const float* left_b = (const float*)d_in[6];
  const float* right_w= (const float*)d_in[7];
  const float* track_w= (const float*)d_in[8];
  const float* w_ih   = (const float*)d_in[9];
  const float* w_hh   = (const float*)d_in[10];
  const float* b_ih   = (const float*)d_in[11];
  const float* b_hh   = (const float*)d_in[12];
  const float* w_out  = (const float*)d_in[13];
  const float* b_out  = (const float*)d_in[14];
  float* out = (float*)d_out;

  char* ws = (char*)d_ws;
  u16* wB    = (u16*)ws;                    // bf16 weight pool
  u16* w_inB = wB;
  u16* w_ihB = wB + 65536;
  u16* w_hhB = wB + 851968;
  u16* w_lB  = wB + 1114112;
  u16* w_rB  = wB + 1441792;
  u16* w_tB  = wB + 1769472;
  u16* buf_s = (u16*)(ws + 4194304);        // [1024][65][256] bf16
  u16* padv  = (u16*)(ws + 38273024);       // [256] bf16
  u16* hR    = (u16*)(ws + 38273536);       // [2][1024][256] bf16
  unsigned* bar = (unsigned*)(ws + 41419264); // 16 groups x {cnt,gen} in 256B slots
  u16* thb   = (u16*)(ws + 42467840);       // [2][1024][256] bf16
  float* lg1 = (float*)(ws + 43516416);     // [63][1024][3] f32

  kprep<<<8192, 256, 0, stream>>>(w_in, w_ih, w_hh, left_w, right_w, track_w, wB);
  kinit<<<760, 256, 0, stream>>>(lg1, bar);
  kbuf2<<<2032, 256, 0, stream>>>(tokens, embed, w_inB, b_in, w_out, b_out, out, buf_s, padv);

  SeqArgs sa;
  sa.buf_s = buf_s; sa.padv = padv; sa.hR = hR; sa.thb = thb;
  sa.w_ihB = w_ihB; sa.w_hhB = w_hhB;
  sa.w_lB = w_lB; sa.w_rB = w_rB; sa.w_tB = w_tB;
  sa.b_ih = b_ih; sa.b_hh = b_hh; sa.b_l = left_b;
  sa.w_out = w_out; sa.lg1 = lg1;
  sa.bar = bar;
  void* kargs[] = { &sa };
  hipLaunchCooperativeKernel((const void*)kseq, dim3(256), dim3(256), kargs, 0, stream);

  kfin<<<252, 256, 0, stream>>>(lg1, b_out, out + 390144);
}

// Round 7
// 2353.538 us; speedup vs baseline: 2.1648x; 1.2899x over previous
//
#include <hip/hip_runtime.h>

typedef unsigned short u16;
typedef unsigned long long u64;
typedef __attribute__((ext_vector_type(8))) short short8;
typedef __attribute__((ext_vector_type(4))) float f32x4;

union U16x8 { uint4 u; short8 s; u16 h[8]; };
struct Frag8 { uint4 v[8]; };

__device__ __forceinline__ float b2f(u16 u) {
  union { unsigned int i; float f; } x; x.i = ((unsigned int)u) << 16; return x.f;
}
__device__ __forceinline__ u16 f2b(float f) {
  union { float f; unsigned int i; } x; x.f = f;
  unsigned int r = x.i + 0x7FFFu + ((x.i >> 16) & 1u);
  return (u16)(r >> 16);
}
__device__ __forceinline__ float sig_(float x) { return 1.0f / (1.0f + __expf(-x)); }
__device__ __forceinline__ float tanh_(float x) {
  float e = __expf(2.0f * x);
  return 1.0f - 2.0f / (e + 1.0f);
}

#define BS_ 16640L  // 65*256, per-batch stride of buf_s

// ---- plain (L2-cached) fragment load ----
__device__ __forceinline__ void plain8(Frag8& f, const u16* p) {
#pragma unroll
  for (int kk = 0; kk < 8; ++kk) f.v[kk] = *(const uint4*)(p + kk * 32);
}

// ---- coherent fragment load from chunked layout: base already includes coff0.
// ---- Two relaxed system-scope u64 atomic loads per 16B chunk; compiler handles
// ---- register allocation and waitcnt placement (no inline asm). ----
__device__ __forceinline__ void ldsys8(Frag8& f, const u16* base) {
#pragma unroll
  for (int kk = 0; kk < 8; ++kk) {
    const u64* p = (const u64*)(base + (size_t)kk * 32768);
    u64 a = __hip_atomic_load(p,     __ATOMIC_RELAXED, __HIP_MEMORY_SCOPE_SYSTEM);
    u64 b = __hip_atomic_load(p + 1, __ATOMIC_RELAXED, __HIP_MEMORY_SCOPE_SYSTEM);
    union { u64 q[2]; uint4 v; } u; u.q[0] = a; u.q[1] = b;
    f.v[kk] = u.v;
  }
}
// ---- coherent 8B store (compiler-generated, correct regalloc) ----
__device__ __forceinline__ void stsys8(u16* p, u64 v) {
  __hip_atomic_store((u64*)p, v, __ATOMIC_RELAXED, __HIP_MEMORY_SCOPE_SYSTEM);
}

// ---------- convert reused weights fp32 -> bf16 into ws ----------
__global__ __launch_bounds__(256) void kprep(
    const float* __restrict__ a0, const float* __restrict__ a1,
    const float* __restrict__ a2, const float* __restrict__ a3,
    const float* __restrict__ a4, const float* __restrict__ a5,
    u16* __restrict__ dst)
{
  int i = blockIdx.x * 256 + threadIdx.x;
  const float* s; int o;
  if (i < 65536)        { s = a0; o = i; }
  else if (i < 851968)  { s = a1; o = i - 65536; }
  else if (i < 1114112) { s = a2; o = i - 851968; }
  else if (i < 1441792) { s = a3; o = i - 1114112; }
  else if (i < 1769472) { s = a4; o = i - 1441792; }
  else                  { s = a5; o = i - 1769472; }
  dst[i] = f2b(s[o]);
}

// ---------- init: zero barrier state ----------
__global__ __launch_bounds__(256) void kinit(unsigned* bar) {
  int i = blockIdx.x * 256 + threadIdx.x;
  if (i < 1024) bar[i] = 0u;
}

// ---------- phase 1 (MFMA): buf = selu(embed[tok] @ W_in^T + b), outputs0 head ----------
__global__ __launch_bounds__(256) void kbuf2(
    const int* __restrict__ tokens, const float* __restrict__ embed,
    const u16* __restrict__ w_inB, const float* __restrict__ b_in,
    const float* __restrict__ w_out, const float* __restrict__ b_out,
    float* __restrict__ out0, u16* __restrict__ buf_s, u16* __restrict__ padv)
{
  __shared__ u16 Wl[128 * 264];
  __shared__ u16 Bufl[64 * 264];
  const int tid = threadIdx.x;
  const int wv = tid >> 6, ln = tid & 63, l15 = ln & 15, lq = ln >> 4;

  int pos = blockIdx.x * 64 + wv * 16 + l15;
  int b = pos / 127, t = pos - b * 127;
  int tok = tokens[b * 127 + t];
  const float* arow = embed + (size_t)tok * 256 + lq * 8;
  short8 av[8];
#pragma unroll
  for (int kk = 0; kk < 8; ++kk) {
    float4 f0 = *(const float4*)(arow + kk * 32);
    float4 f1 = *(const float4*)(arow + kk * 32 + 4);
    U16x8 tmp;
    tmp.h[0] = f2b(f0.x); tmp.h[1] = f2b(f0.y); tmp.h[2] = f2b(f0.z); tmp.h[3] = f2b(f0.w);
    tmp.h[4] = f2b(f1.x); tmp.h[5] = f2b(f1.y); tmp.h[6] = f2b(f1.z); tmp.h[7] = f2b(f1.w);
    av[kk] = tmp.s;
  }

  const float SELU_A = 1.6732632423543772f, SELU_S = 1.0507009873554805f;
#pragma unroll 1
  for (int hf = 0; hf < 2; ++hf) {
    __syncthreads();
    {
      int col = tid >> 1, seg = tid & 1;
      const uint4* s = (const uint4*)(w_inB + (size_t)(hf * 128 + col) * 256 + seg * 128);
      uint4* d = (uint4*)(Wl + col * 264 + seg * 128);
#pragma unroll
      for (int i = 0; i < 16; ++i) d[i] = s[i];
    }
    __syncthreads();
#pragma unroll 1
    for (int t2 = 0; t2 < 8; ++t2) {
      f32x4 acc = {0.f, 0.f, 0.f, 0.f};
#pragma unroll
      for (int kk = 0; kk < 8; ++kk) {
        U16x8 bv; bv.u = *(const uint4*)(Wl + (t2 * 16 + l15) * 264 + kk * 32 + lq * 8);
        acc = __builtin_amdgcn_mfma_f32_16x16x32_bf16(av[kk], bv.s, acc, 0, 0, 0);
      }
      int col = hf * 128 + t2 * 16 + l15;
      float bi = b_in[col];
#pragma unroll
      for (int i = 0; i < 4; ++i) {
        float v = acc[i] + bi;
        v = (v > 0.0f) ? SELU_S * v : SELU_S * SELU_A * (__expf(v) - 1.0f);
        Bufl[(wv * 16 + lq * 4 + i) * 264 + col] = f2b(v);
      }
    }
  }
  __syncthreads();

  {
    int row = tid >> 2, seg = tid & 3;
    int pos2 = blockIdx.x * 64 + row;
    int b2 = pos2 / 127, t2p = pos2 - b2 * 127;
    u16* dst = 0;
    if (t2p <= 64) dst = buf_s + (size_t)b2 * BS_ + t2p * 256 + seg * 64;
    else if (t2p == 126 && b2 == 0) dst = padv + seg * 64;
    if (dst) {
      const uint4* s = (const uint4*)(Bufl + row * 264 + seg * 64);
      uint4* d = (uint4*)dst;
#pragma unroll
      for (int i = 0; i < 8; ++i) d[i] = s[i];
    }
  }
#pragma unroll 1
  for (int pp = 0; pp < 16; ++pp) {
    int p = wv * 16 + pp;
    uint2 hu = *(const uint2*)(Bufl + p * 264 + ln * 4);
    const u16* hh = (const u16*)&hu;
    float lg[3];
#pragma unroll
    for (int o = 0; o < 3; ++o) {
      float4 wvv = *(const float4*)(w_out + o * 256 + ln * 4);
      lg[o] = b2f(hh[0]) * wvv.x + b2f(hh[1]) * wvv.y + b2f(hh[2]) * wvv.z + b2f(hh[3]) * wvv.w;
    }
#pragma unroll
    for (int o = 0; o < 3; ++o)
      for (int off = 32; off > 0; off >>= 1) lg[o] += __shfl_down(lg[o], off);
    if (ln == 0) {
      float l0 = lg[0] + b_out[0];
      float l1 = lg[1] + b_out[1];
      float l2 = lg[2] + b_out[2];
      float m = fmaxf(l0, fmaxf(l1, l2));
      float lse = m + __logf(__expf(l0 - m) + __expf(l1 - m) + __expf(l2 - m));
      int pos3 = blockIdx.x * 64 + p;
      int b3 = pos3 / 127, t3 = pos3 - b3 * 127;
      size_t o0 = ((size_t)t3 * 1024 + b3) * 3;
      out0[o0 + 0] = l0 - lse;
      out0[o0 + 1] = l1 - lse;
      out0[o0 + 2] = l2 - lse;
    }
  }
}

// ---------- per-group (16-block) barrier: R4-proven asm protocol ----------
__device__ __forceinline__ void groupbar(unsigned* cnt, unsigned* gen, unsigned k) {
  asm volatile("s_waitcnt vmcnt(0)" ::: "memory");  // drain this wave's coherent stores
  __syncthreads();
  if (threadIdx.x == 0) {
    unsigned prev, one = 1u;
    asm volatile("global_atomic_add %0, %1, %2, off sc0 sc1\n\ts_waitcnt vmcnt(0)"
                 : "=&v"(prev) : "v"(cnt), "v"(one) : "memory");
    if (prev == k * 16u - 1u) {
      asm volatile("global_store_dword %0, %1, off sc0 sc1" :: "v"(gen), "v"(k) : "memory");
    }
    unsigned g = 0, guard = 0;
    for (;;) {
      asm volatile("global_load_dword %0, %1, off sc0 sc1\n\ts_waitcnt vmcnt(0)"
                   : "=&v"(g) : "v"(gen) : "memory");
      if (g >= k) break;
      __builtin_amdgcn_s_sleep(1);
      if (++guard > (1u << 22)) break;  // escape hatch: fail visibly, never hang
    }
  }
  __syncthreads();
}

struct SeqArgs {
  const u16* buf_s; const u16* padv; u16* hRc; u16* thc;
  const u16* w_ihB; const u16* w_hhB;
  const u16* w_lB; const u16* w_rB; const u16* w_tB;
  const float* b_ih; const float* b_hh; const float* b_l;
  const float* w_out;
  float* lgp;
  unsigned* bar;
};

// ---------- persistent sequential phase: 127 tracker + 63 reduce steps ----------
// th/hR in chunked layout: [colblock n(16)][row(1024)][16 cols] bf16.
__global__ __launch_bounds__(256, 1) void kseq(SeqArgs A) {
  __shared__ u16 Wt[64 * 1048];             // tracker W slice, resident all steps
  __shared__ __align__(16) u16 Th[64 * 24]; // staging tile for coalesced stores
  const int tid = threadIdx.x;
  const int bid = blockIdx.x;
  const int m = bid & 15, n = bid >> 4;  // group m: 16 col-blocks over rows m*64..+63
  {
    int col = tid >> 2, kseg = (tid & 3) * 256;
    int nr = (col >> 4) * 256 + n * 16 + (col & 15);
    const uint4* s = (const uint4*)((kseg < 768) ? (A.w_ihB + (size_t)nr * 768 + kseg)
                                                 : (A.w_hhB + (size_t)nr * 256));
    uint4* d = (uint4*)(Wt + col * 1048 + kseg);
#pragma unroll 8
    for (int i = 0; i < 32; ++i) d[i] = s[i];
  }
  const int wv = tid >> 6, ln = tid & 63, l15 = ln & 15, lq = ln >> 4;
  const long grow = (long)m * 64 + wv * 16 + l15;  // this lane's A-row
  const int c = n * 16 + l15;
  const int erow0 = m * 64 + wv * 16 + lq * 4;
  unsigned* bcnt = A.bar + m * 64;
  unsigned* bgen = A.bar + m * 64 + 16;
  // chunked-fragment base: chunk = 2*kk + (lq>>1), offset = 8*(lq&1); frag kk at +kk*32768
  const size_t coff0 = (size_t)((lq >> 1) * 1024 + grow) * 16 + 8 * (lq & 1);
  float bt[4], br[5], wo[3];
#pragma unroll
  for (int q = 0; q < 4; ++q) bt[q] = A.b_ih[q * 256 + c] + A.b_hh[q * 256 + c];
#pragma unroll
  for (int q = 0; q < 5; ++q) br[q] = A.b_l[q * 256 + c];
#pragma unroll
  for (int o = 0; o < 3; ++o) wo[o] = A.w_out[o * 256 + c];
  float tcv[4] = {0.f, 0.f, 0.f, 0.f};
  float rcv[4] = {0.f, 0.f, 0.f, 0.f};
  __syncthreads();

  const u16* bufs = A.buf_s;
  unsigned bk = 0;
#pragma unroll 1
  for (int t = 0; t < 127; ++t) {
    // ---- static schedule ----
    const u16 *A1, *A2; long S1, S2; int k; bool isR = false, c1 = false, c2 = false;
    if (t == 0)      { k = 0;  A1 = A.padv; S1 = 0;   A2 = A.padv; S2 = 0; }
    else if (t == 1) { k = 1;  A1 = bufs;            S1 = BS_; A2 = A.padv; S2 = 0; }
    else if (t == 2) { k = 2;  A1 = bufs + 256;      S1 = BS_; A2 = bufs;       S2 = BS_; }
    else if (t == 3) { k = 3;  A1 = bufs + 512;      S1 = BS_; A2 = bufs + 256; S2 = BS_; isR = true; }
    else if (t == 126) { k = 64; A1 = A.hRc + (62 & 1) * 262144; c1 = true; S1 = 0; A2 = bufs; S2 = BS_; isR = true; }
    else if ((t & 1) == 0) { int i = (t - 2) / 2; k = i + 2; A1 = A.hRc + (size_t)(i & 1) * 262144; c1 = true; S1 = 0; A2 = bufs; S2 = BS_; }
    else { int i = (t - 3) / 2; k = i + 3; A1 = bufs + (i + 2) * 256; S1 = BS_; A2 = A.hRc + (size_t)(i & 1) * 262144; c2 = true; S2 = 0; isR = true; }

    const u16* thin = A.thc + (size_t)(t & 1) * 262144;
    u16* thout = A.thc + (size_t)((t + 1) & 1) * 262144;

    // ---- gather 4 A-channel fragments ----
    Frag8 f0, f1, f2, f3;
    plain8(f0, bufs + k * 256 + grow * BS_ + 8 * lq);
    if (t == 0) {
      plain8(f1, A1 + grow * S1 + 8 * lq);
      plain8(f2, A2 + grow * S2 + 8 * lq);
#pragma unroll
      for (int kk = 0; kk < 8; ++kk) f3.v[kk] = make_uint4(0, 0, 0, 0);
    } else if (c1) {
      plain8(f2, A2 + grow * S2 + 8 * lq);
      ldsys8(f1, A1 + coff0);
      ldsys8(f3, thin + coff0);
    } else if (c2) {
      plain8(f1, A1 + grow * S1 + 8 * lq);
      ldsys8(f2, A2 + coff0);
      ldsys8(f3, thin + coff0);
    } else {
      plain8(f1, A1 + grow * S1 + 8 * lq);
      plain8(f2, A2 + grow * S2 + 8 * lq);
      ldsys8(f3, thin + coff0);
    }

    // ---- tracker MFMA ----
    f32x4 acc[4] = { {0.f,0.f,0.f,0.f}, {0.f,0.f,0.f,0.f}, {0.f,0.f,0.f,0.f}, {0.f,0.f,0.f,0.f} };
    const Frag8* fs[4] = { &f0, &f1, &f2, &f3 };
#pragma unroll
    for (int ch = 0; ch < 4; ++ch) {
#pragma unroll
      for (int kk = 0; kk < 8; ++kk) {
        U16x8 avv; avv.u = fs[ch]->v[kk];
#pragma unroll
        for (int qt = 0; qt < 4; ++qt) {
          U16x8 bv; bv.u = *(const uint4*)(Wt + (qt * 16 + l15) * 1048 + ch * 256 + kk * 32 + 8 * lq);
          acc[qt] = __builtin_amdgcn_mfma_f32_16x16x32_bf16(avv.s, bv.s, acc[qt], 0, 0, 0);
        }
      }
    }
#pragma unroll
    for (int i = 0; i < 4; ++i) {
      float gi = acc[0][i] + bt[0];
      float gf = acc[1][i] + bt[1];
      float gg = acc[2][i] + bt[2];
      float go = acc[3][i] + bt[3];
      float tcn = sig_(gf) * tcv[i] + sig_(gi) * tanh_(gg);
      tcv[i] = tcn;
      Th[(wv * 16 + lq * 4 + i) * 24 + l15] = f2b(sig_(go) * tanh_(tcn));
    }
    __syncthreads();
    {  // coalesced coherent store of this block's 64x16 th tile (256 x 8B)
      int r = tid >> 2, q = tid & 3;
      u64 vv = *(const u64*)(Th + r * 24 + q * 4);
      stsys8(thout + ((size_t)n * 1024 + m * 64 + r) * 16 + q * 4, vv);
    }
    ++bk; groupbar(bcnt, bgen, bk);

    if (isR) {
      int j; const u16 *lH, *rH; long lHs, rHs; int lcase; const u16 *lCg = 0, *rCg = 0;
      if (t == 3) { j = 1; lH = bufs + 256; lHs = BS_; rH = bufs + 512; rHs = BS_;
                    lcase = 0; lCg = bufs + 256; rCg = bufs + 512; }
      else if (t == 126) { j = 63; lH = bufs; lHs = BS_; rH = A.hRc + (62 & 1) * 262144; rHs = 0;
                    lcase = 2; lCg = bufs; }
      else { int i2 = (t - 3) / 2; j = i2 + 1; lH = A.hRc + (size_t)(i2 & 1) * 262144; lHs = 0;
             rH = bufs + (i2 + 2) * 256; rHs = BS_; lcase = 1; rCg = bufs + (i2 + 2) * 256; }

      Frag8 fL, fR, fT;
      if (lcase == 0) {
        plain8(fL, lH + grow * lHs + 8 * lq);
        plain8(fR, rH + grow * rHs + 8 * lq);
        ldsys8(fT, thout + coff0);
      } else if (lcase == 2) {
        plain8(fL, lH + grow * lHs + 8 * lq);
        ldsys8(fR, rH + coff0);
        ldsys8(fT, thout + coff0);
      } else {
        plain8(fR, rH + grow * rHs + 8 * lq);
        ldsys8(fL, lH + coff0);
        ldsys8(fT, thout + coff0);
      }

      f32x4 acc2[5] = { {0.f,0.f,0.f,0.f}, {0.f,0.f,0.f,0.f}, {0.f,0.f,0.f,0.f},
                        {0.f,0.f,0.f,0.f}, {0.f,0.f,0.f,0.f} };
      const Frag8* fr[3] = { &fL, &fR, &fT };
      const u16* wch[3] = { A.w_lB, A.w_rB, A.w_tB };
#pragma unroll
      for (int ch = 0; ch < 3; ++ch) {
        const u16* wb = wch[ch];
#pragma unroll
        for (int kk = 0; kk < 8; ++kk) {
          U16x8 avv; avv.u = fr[ch]->v[kk];
#pragma unroll
          for (int ct = 0; ct < 5; ++ct) {
            U16x8 bv; bv.u = *(const uint4*)(wb + (size_t)(ct * 256 + c) * 256 + kk * 32 + 8 * lq);
            acc2[ct] = __builtin_amdgcn_mfma_f32_16x16x32_bf16(avv.s, bv.s, acc2[ct], 0, 0, 0);
          }
        }
      }
      u16* oH = A.hRc + (size_t)(j & 1) * 262144;
      float hv4[4];
#pragma unroll
      for (int i = 0; i < 4; ++i) {
        int row = erow0 + i;
        float a_ = acc2[0][i] + br[0];
        float ig = acc2[1][i] + br[1];
        float f1g = acc2[2][i] + br[2];
        float f2g = acc2[3][i] + br[3];
        float og = acc2[4][i] + br[4];
        float lc = (lcase == 1) ? rcv[i] : b2f(lCg[(size_t)row * BS_ + c]);
        float rc = (lcase == 2) ? rcv[i] : b2f(rCg[(size_t)row * BS_ + c]);
        float cn = tanh_(a_) * sig_(ig) + sig_(f1g) * lc + sig_(f2g) * rc;
        float hn = sig_(og) * tanh_(cn);
        rcv[i] = cn;
        Th[(wv * 16 + lq * 4 + i) * 24 + l15] = f2b(hn);
        hv4[i] = hn;
      }
      // per-block head-logit partials (plain stores; disjoint ownership; kfin reduces)
      float pr[12];
#pragma unroll
      for (int o = 0; o < 3; ++o)
#pragma unroll
        for (int i = 0; i < 4; ++i) pr[o * 4 + i] = hv4[i] * wo[o];
#pragma unroll
      for (int u = 0; u < 12; ++u)
#pragma unroll
        for (int mm = 1; mm < 16; mm <<= 1) pr[u] += __shfl_xor(pr[u], mm);
      if (l15 == 0) {
        float* lgo = A.lgp + (size_t)((j - 1) * 16 + n) * 3072;
#pragma unroll
        for (int o = 0; o < 3; ++o)
#pragma unroll
          for (int i = 0; i < 4; ++i)
            lgo[(size_t)(erow0 + i) * 3 + o] = pr[o * 4 + i];
      }
      __syncthreads();
      {  // coalesced coherent store of this block's 64x16 hR tile
        int r = tid >> 2, q = tid & 3;
        u64 vv = *(const u64*)(Th + r * 24 + q * 4);
        stsys8(oH + ((size_t)n * 1024 + m * 64 + r) * 16 + q * 4, vv);
      }
      ++bk; groupbar(bcnt, bgen, bk);
    }
  }
}

// ---------- finalize outs1: sum 16 per-block partials, log-softmax ----------
__global__ __launch_bounds__(256) void kfin(const float* __restrict__ lgp,
    const float* __restrict__ b_out, float* __restrict__ out1)
{
  int r = blockIdx.x * 256 + threadIdx.x;
  if (r >= 64512) return;
  int j = r >> 10, row = r & 1023;
  float l0 = b_out[0], l1 = b_out[1], l2 = b_out[2];
#pragma unroll
  for (int nn = 0; nn < 16; ++nn) {
    const float* p = lgp + ((size_t)(j * 16 + nn) * 1024 + row) * 3;
    l0 += p[0]; l1 += p[1]; l2 += p[2];
  }
  float m = fmaxf(l0, fmaxf(l1, l2));
  float lse = m + __logf(__expf(l0 - m) + __expf(l1 - m) + __expf(l2 - m));
  out1[r * 3 + 0] = l0 - lse;
  out1[r * 3 + 1] = l1 - lse;
  out1[r * 3 + 2] = l2 - lse;
}

extern "C" void kernel_launch(void* const* d_in, const int* in_sizes, int n_in,
                              void* d_out, int out_size, void* d_ws, size_t ws_size,
                              hipStream_t stream) {
  const int* tokens   = (const int*)d_in[0];
  const float* embed  = (const float*)d_in[2];
  const float* w_in   = (const float*)d_in[3];
  const float* b_in   = (const float*)d_in[4];
  const float* left_w = (const float*)d_in[5];
  const float* left_b = (const float*)d_in[6];
  const float* right_w= (const float*)d_in[7];
  const float* track_w= (const float*)d_in[8];
  const float* w_ih   = (const float*)d_in[9];
  const float* w_hh   = (const float*)d_in[10];
  const float* b_ih   = (const float*)d_in[11];
  const float* b_hh   = (const float*)d_in[12];
  const float* w_out  = (const float*)d_in[13];
  const float* b_out  = (const float*)d_in[14];
  float* out = (float*)d_out;

  char* ws = (char*)d_ws;
  u16* wB    = (u16*)ws;                      // bf16 weight pool (4 MB)
  u16* w_inB = wB;
  u16* w_ihB = wB + 65536;
  u16* w_hhB = wB + 851968;
  u16* w_lB  = wB + 1114112;
  u16* w_rB  = wB + 1441792;
  u16* w_tB  = wB + 1769472;
  u16* buf_s = (u16*)(ws + 4194304);          // [1024][65][256] bf16
  u16* padv  = (u16*)(ws + 38273024);         // [256] bf16
  u16* thc   = (u16*)(ws + 38273536);         // [2] chunked th, 512 KB each
  u16* hRc   = (u16*)(ws + 39322112);         // [2] chunked hR, 512 KB each
  unsigned* bar = (unsigned*)(ws + 40370688); // 16 groups x {cnt,gen}
  float* lgp = (float*)(ws + 40374784);       // [63][16][1024][3] f32 partials

  kprep<<<8192, 256, 0, stream>>>(w_in, w_ih, w_hh, left_w, right_w, track_w, wB);
  kinit<<<4, 256, 0, stream>>>(bar);
  kbuf2<<<2032, 256, 0, stream>>>(tokens, embed, w_inB, b_in, w_out, b_out, out, buf_s, padv);

  SeqArgs sa;
  sa.buf_s = buf_s; sa.padv = padv; sa.hRc = hRc; sa.thc = thc;
  sa.w_ihB = w_ihB; sa.w_hhB = w_hhB;
  sa.w_lB = w_lB; sa.w_rB = w_rB; sa.w_tB = w_tB;
  sa.b_ih = b_ih; sa.b_hh = b_hh; sa.b_l = left_b;
  sa.w_out = w_out; sa.lgp = lgp;
  sa.bar = bar;
  void* kargs[] = { &sa };
  hipLaunchCooperativeKernel((const void*)kseq, dim3(256), dim3(256), kargs, 0, stream);

  kfin<<<252, 256, 0, stream>>>(lgp, b_out, out + 390144);
}

// Round 12
// 2344.354 us; speedup vs baseline: 2.1733x; 1.0039x over previous
//
#include <hip/hip_runtime.h>

typedef unsigned short u16;
typedef unsigned long long u64;
typedef __attribute__((ext_vector_type(8))) short short8;
typedef __attribute__((ext_vector_type(4))) float f32x4;

union U16x8 { uint4 u; short8 s; u16 h[8]; };
struct Frag8 { uint4 v[8]; };

__device__ __forceinline__ float b2f(u16 u) {
  union { unsigned int i; float f; } x; x.i = ((unsigned int)u) << 16; return x.f;
}
__device__ __forceinline__ u16 f2b(float f) {
  union { float f; unsigned int i; } x; x.f = f;
  unsigned int r = x.i + 0x7FFFu + ((x.i >> 16) & 1u);
  return (u16)(r >> 16);
}
__device__ __forceinline__ float sig_(float x) { return 1.0f / (1.0f + __expf(-x)); }
__device__ __forceinline__ float tanh_(float x) {
  float e = __expf(2.0f * x);
  return 1.0f - 2.0f / (e + 1.0f);
}

#define BS_ 16640L  // 65*256, per-batch stride of buf_s

// ---- plain (L1/L2-cached) fragment load ----
__device__ __forceinline__ void plain8(Frag8& f, const u16* p) {
#pragma unroll
  for (int kk = 0; kk < 8; ++kk) f.v[kk] = *(const uint4*)(p + kk * 32);
}

// ---- coherent fragment load from chunked layout: base already includes coff0.
// ---- Two relaxed system-scope u64 atomic loads per 16B chunk; compiler handles
// ---- register allocation and waitcnt placement (no inline asm). ----
__device__ __forceinline__ void ldsys8(Frag8& f, const u16* base) {
#pragma unroll
  for (int kk = 0; kk < 8; ++kk) {
    const u64* p = (const u64*)(base + (size_t)kk * 32768);
    u64 a = __hip_atomic_load(p,     __ATOMIC_RELAXED, __HIP_MEMORY_SCOPE_SYSTEM);
    u64 b = __hip_atomic_load(p + 1, __ATOMIC_RELAXED, __HIP_MEMORY_SCOPE_SYSTEM);
    union { u64 q[2]; uint4 v; } u; u.q[0] = a; u.q[1] = b;
    f.v[kk] = u.v;
  }
}
// ---- coherent 8B store (compiler-generated, correct regalloc) ----
__device__ __forceinline__ void stsys8(u16* p, u64 v) {
  __hip_atomic_store((u64*)p, v, __ATOMIC_RELAXED, __HIP_MEMORY_SCOPE_SYSTEM);
}

// ---------- convert reused weights fp32 -> bf16 into ws ----------
__global__ __launch_bounds__(256) void kprep(
    const float* __restrict__ a0, const float* __restrict__ a1,
    const float* __restrict__ a2, const float* __restrict__ a3,
    const float* __restrict__ a4, const float* __restrict__ a5,
    u16* __restrict__ dst)
{
  int i = blockIdx.x * 256 + threadIdx.x;
  const float* s; int o;
  if (i < 65536)        { s = a0; o = i; }
  else if (i < 851968)  { s = a1; o = i - 65536; }
  else if (i < 1114112) { s = a2; o = i - 851968; }
  else if (i < 1441792) { s = a3; o = i - 1114112; }
  else if (i < 1769472) { s = a4; o = i - 1441792; }
  else                  { s = a5; o = i - 1769472; }
  dst[i] = f2b(s[o]);
}

// ---------- init: zero barrier state ----------
__global__ __launch_bounds__(256) void kinit(unsigned* bar) {
  int i = blockIdx.x * 256 + threadIdx.x;
  if (i < 1024) bar[i] = 0u;
}

// ---------- phase 1 (MFMA): buf = selu(embed[tok] @ W_in^T + b), outputs0 head ----------
__global__ __launch_bounds__(256) void kbuf2(
    const int* __restrict__ tokens, const float* __restrict__ embed,
    const u16* __restrict__ w_inB, const float* __restrict__ b_in,
    const float* __restrict__ w_out, const float* __restrict__ b_out,
    float* __restrict__ out0, u16* __restrict__ buf_s, u16* __restrict__ padv)
{
  __shared__ u16 Wl[128 * 264];
  __shared__ u16 Bufl[64 * 264];
  const int tid = threadIdx.x;
  const int wv = tid >> 6, ln = tid & 63, l15 = ln & 15, lq = ln >> 4;

  int pos = blockIdx.x * 64 + wv * 16 + l15;
  int b = pos / 127, t = pos - b * 127;
  int tok = tokens[b * 127 + t];
  const float* arow = embed + (size_t)tok * 256 + lq * 8;
  short8 av[8];
#pragma unroll
  for (int kk = 0; kk < 8; ++kk) {
    float4 f0 = *(const float4*)(arow + kk * 32);
    float4 f1 = *(const float4*)(arow + kk * 32 + 4);
    U16x8 tmp;
    tmp.h[0] = f2b(f0.x); tmp.h[1] = f2b(f0.y); tmp.h[2] = f2b(f0.z); tmp.h[3] = f2b(f0.w);
    tmp.h[4] = f2b(f1.x); tmp.h[5] = f2b(f1.y); tmp.h[6] = f2b(f1.z); tmp.h[7] = f2b(f1.w);
    av[kk] = tmp.s;
  }

  const float SELU_A = 1.6732632423543772f, SELU_S = 1.0507009873554805f;
#pragma unroll 1
  for (int hf = 0; hf < 2; ++hf) {
    __syncthreads();
    {
      int col = tid >> 1, seg = tid & 1;
      const uint4* s = (const uint4*)(w_inB + (size_t)(hf * 128 + col) * 256 + seg * 128);
      uint4* d = (uint4*)(Wl + col * 264 + seg * 128);
#pragma unroll
      for (int i = 0; i < 16; ++i) d[i] = s[i];
    }
    __syncthreads();
#pragma unroll 1
    for (int t2 = 0; t2 < 8; ++t2) {
      f32x4 acc = {0.f, 0.f, 0.f, 0.f};
#pragma unroll
      for (int kk = 0; kk < 8; ++kk) {
        U16x8 bv; bv.u = *(const uint4*)(Wl + (t2 * 16 + l15) * 264 + kk * 32 + lq * 8);
        acc = __builtin_amdgcn_mfma_f32_16x16x32_bf16(av[kk], bv.s, acc, 0, 0, 0);
      }
      int col = hf * 128 + t2 * 16 + l15;
      float bi = b_in[col];
#pragma unroll
      for (int i = 0; i < 4; ++i) {
        float v = acc[i] + bi;
        v = (v > 0.0f) ? SELU_S * v : SELU_S * SELU_A * (__expf(v) - 1.0f);
        Bufl[(wv * 16 + lq * 4 + i) * 264 + col] = f2b(v);
      }
    }
  }
  __syncthreads();

  {
    int row = tid >> 2, seg = tid & 3;
    int pos2 = blockIdx.x * 64 + row;
    int b2 = pos2 / 127, t2p = pos2 - b2 * 127;
    u16* dst = 0;
    if (t2p <= 64) dst = buf_s + (size_t)b2 * BS_ + t2p * 256 + seg * 64;
    else if (t2p == 126 && b2 == 0) dst = padv + seg * 64;
    if (dst) {
      const uint4* s = (const uint4*)(Bufl + row * 264 + seg * 64);
      uint4* d = (uint4*)dst;
#pragma unroll
      for (int i = 0; i < 8; ++i) d[i] = s[i];
    }
  }
#pragma unroll 1
  for (int pp = 0; pp < 16; ++pp) {
    int p = wv * 16 + pp;
    uint2 hu = *(const uint2*)(Bufl + p * 264 + ln * 4);
    const u16* hh = (const u16*)&hu;
    float lg[3];
#pragma unroll
    for (int o = 0; o < 3; ++o) {
      float4 wvv = *(const float4*)(w_out + o * 256 + ln * 4);
      lg[o] = b2f(hh[0]) * wvv.x + b2f(hh[1]) * wvv.y + b2f(hh[2]) * wvv.z + b2f(hh[3]) * wvv.w;
    }
#pragma unroll
    for (int o = 0; o < 3; ++o)
      for (int off = 32; off > 0; off >>= 1) lg[o] += __shfl_down(lg[o], off);
    if (ln == 0) {
      float l0 = lg[0] + b_out[0];
      float l1 = lg[1] + b_out[1];
      float l2 = lg[2] + b_out[2];
      float m = fmaxf(l0, fmaxf(l1, l2));
      float lse = m + __logf(__expf(l0 - m) + __expf(l1 - m) + __expf(l2 - m));
      int pos3 = blockIdx.x * 64 + p;
      int b3 = pos3 / 127, t3 = pos3 - b3 * 127;
      size_t o0 = ((size_t)t3 * 1024 + b3) * 3;
      out0[o0 + 0] = l0 - lse;
      out0[o0 + 1] = l1 - lse;
      out0[o0 + 2] = l2 - lse;
    }
  }
}

// ---------- per-group (16-block) barrier: R4-proven asm protocol ----------
__device__ __forceinline__ void groupbar(unsigned* cnt, unsigned* gen, unsigned k) {
  asm volatile("s_waitcnt vmcnt(0)" ::: "memory");  // drain this wave's coherent stores
  __syncthreads();
  if (threadIdx.x == 0) {
    unsigned prev, one = 1u;
    asm volatile("global_atomic_add %0, %1, %2, off sc0 sc1\n\ts_waitcnt vmcnt(0)"
                 : "=&v"(prev) : "v"(cnt), "v"(one) : "memory");
    if (prev == k * 16u - 1u) {
      asm volatile("global_store_dword %0, %1, off sc0 sc1" :: "v"(gen), "v"(k) : "memory");
    }
    unsigned g = 0, guard = 0;
    for (;;) {
      asm volatile("global_load_dword %0, %1, off sc0 sc1\n\ts_waitcnt vmcnt(0)"
                   : "=&v"(g) : "v"(gen) : "memory");
      if (g >= k) break;
      __builtin_amdgcn_s_sleep(1);
      if (++guard > (1u << 22)) break;  // escape hatch: fail visibly, never hang
    }
  }
  __syncthreads();
}

struct SeqArgs {
  const u16* buf_s; const u16* padv; u16* hRc; u16* thc;
  const u16* w_ihB; const u16* w_hhB;
  const u16* w_lB; const u16* w_rB; const u16* w_tB;
  const float* b_ih; const float* b_hh; const float* b_l;
  const float* w_out;
  float* lgp;
  unsigned* bar;
};

// ---------- persistent sequential phase: 127 tracker + 63 reduce steps ----------
// th/hR in chunked layout: [colblock n(16)][row(1024)][16 cols] bf16.
__global__ __launch_bounds__(256, 1) void kseq(SeqArgs A) {
  __shared__ u16 Wt[64 * 1048];             // tracker W slice, resident all steps
  __shared__ __align__(16) u16 Th[64 * 24]; // staging tile for coalesced stores
  const int tid = threadIdx.x;
  const int bid = blockIdx.x;
  const int m = bid & 15, n = bid >> 4;  // group m: 16 col-blocks over rows m*64..+63
  {
    int col = tid >> 2, kseg = (tid & 3) * 256;
    int nr = (col >> 4) * 256 + n * 16 + (col & 15);
    const uint4* s = (const uint4*)((kseg < 768) ? (A.w_ihB + (size_t)nr * 768 + kseg)
                                                 : (A.w_hhB + (size_t)nr * 256));
    uint4* d = (uint4*)(Wt + col * 1048 + kseg);
#pragma unroll 8
    for (int i = 0; i < 32; ++i) d[i] = s[i];
  }
  const int wv = tid >> 6, ln = tid & 63, l15 = ln & 15, lq = ln >> 4;
  const long grow = (long)m * 64 + wv * 16 + l15;  // this lane's A-row
  const int c = n * 16 + l15;
  const int erow0 = m * 64 + wv * 16 + lq * 4;
  unsigned* bcnt = A.bar + m * 64;
  unsigned* bgen = A.bar + m * 64 + 16;
  // chunked-fragment base: chunk = 2*kk + (lq>>1), offset = 8*(lq&1); frag kk at +kk*32768
  const size_t coff0 = (size_t)((lq >> 1) * 1024 + grow) * 16 + 8 * (lq & 1);
  float bt[4], br[5], wo[3];
#pragma unroll
  for (int q = 0; q < 4; ++q) bt[q] = A.b_ih[q * 256 + c] + A.b_hh[q * 256 + c];
#pragma unroll
  for (int q = 0; q < 5; ++q) br[q] = A.b_l[q * 256 + c];
#pragma unroll
  for (int o = 0; o < 3; ++o) wo[o] = A.w_out[o * 256 + c];
  float tcv[4] = {0.f, 0.f, 0.f, 0.f};
  float rcv[4] = {0.f, 0.f, 0.f, 0.f};
  __syncthreads();

  const u16* bufs = A.buf_s;
  unsigned bk = 0;
#pragma unroll 1
  for (int t = 0; t < 127; ++t) {
    // ---- static schedule ----
    const u16 *A1, *A2; long S1, S2; int k; bool isR = false, c1 = false, c2 = false;
    if (t == 0)      { k = 0;  A1 = A.padv; S1 = 0;   A2 = A.padv; S2 = 0; }
    else if (t == 1) { k = 1;  A1 = bufs;            S1 = BS_; A2 = A.padv; S2 = 0; }
    else if (t == 2) { k = 2;  A1 = bufs + 256;      S1 = BS_; A2 = bufs;       S2 = BS_; }
    else if (t == 3) { k = 3;  A1 = bufs + 512;      S1 = BS_; A2 = bufs + 256; S2 = BS_; isR = true; }
    else if (t == 126) { k = 64; A1 = A.hRc + (62 & 1) * 262144; c1 = true; S1 = 0; A2 = bufs; S2 = BS_; isR = true; }
    else if ((t & 1) == 0) { int i = (t - 2) / 2; k = i + 2; A1 = A.hRc + (size_t)(i & 1) * 262144; c1 = true; S1 = 0; A2 = bufs; S2 = BS_; }
    else { int i = (t - 3) / 2; k = i + 3; A1 = bufs + (i + 2) * 256; S1 = BS_; A2 = A.hRc + (size_t)(i & 1) * 262144; c2 = true; S2 = 0; isR = true; }

    const u16* thin = A.thc + (size_t)(t & 1) * 262144;
    u16* thout = A.thc + (size_t)((t + 1) & 1) * 262144;

    // ---- gather 4 A-channel fragments ----
    Frag8 f0, f1, f2, f3;
    plain8(f0, bufs + k * 256 + grow * BS_ + 8 * lq);
    if (t == 0) {
      plain8(f1, A1 + grow * S1 + 8 * lq);
      plain8(f2, A2 + grow * S2 + 8 * lq);
#pragma unroll
      for (int kk = 0; kk < 8; ++kk) f3.v[kk] = make_uint4(0, 0, 0, 0);
    } else if (c1) {
      plain8(f2, A2 + grow * S2 + 8 * lq);
      ldsys8(f1, A1 + coff0);
      ldsys8(f3, thin + coff0);
    } else if (c2) {
      plain8(f1, A1 + grow * S1 + 8 * lq);
      ldsys8(f2, A2 + coff0);
      ldsys8(f3, thin + coff0);
    } else {
      plain8(f1, A1 + grow * S1 + 8 * lq);
      plain8(f2, A2 + grow * S2 + 8 * lq);
      ldsys8(f3, thin + coff0);
    }

    // ---- tracker MFMA ----
    f32x4 acc[4] = { {0.f,0.f,0.f,0.f}, {0.f,0.f,0.f,0.f}, {0.f,0.f,0.f,0.f}, {0.f,0.f,0.f,0.f} };
    const Frag8* fs[4] = { &f0, &f1, &f2, &f3 };
#pragma unroll
    for (int ch = 0; ch < 4; ++ch) {
#pragma unroll
      for (int kk = 0; kk < 8; ++kk) {
        U16x8 avv; avv.u = fs[ch]->v[kk];
#pragma unroll
        for (int qt = 0; qt < 4; ++qt) {
          U16x8 bv; bv.u = *(const uint4*)(Wt + (qt * 16 + l15) * 1048 + ch * 256 + kk * 32 + 8 * lq);
          acc[qt] = __builtin_amdgcn_mfma_f32_16x16x32_bf16(avv.s, bv.s, acc[qt], 0, 0, 0);
        }
      }
    }
#pragma unroll
    for (int i = 0; i < 4; ++i) {
      float gi = acc[0][i] + bt[0];
      float gf = acc[1][i] + bt[1];
      float gg = acc[2][i] + bt[2];
      float go = acc[3][i] + bt[3];
      float tcn = sig_(gf) * tcv[i] + sig_(gi) * tanh_(gg);
      tcv[i] = tcn;
      Th[(wv * 16 + lq * 4 + i) * 24 + l15] = f2b(sig_(go) * tanh_(tcn));
    }
    __syncthreads();
    {  // coalesced coherent store of this block's 64x16 th tile (256 x 8B)
      int r = tid >> 2, q = tid & 3;
      u64 vv = *(const u64*)(Th + r * 24 + q * 4);
      stsys8(thout + ((size_t)n * 1024 + m * 64 + r) * 16 + q * 4, vv);
    }
    ++bk; groupbar(bcnt, bgen, bk);

    if (isR) {
      int j; const u16 *lH, *rH; long lHs, rHs; int lcase; const u16 *lCg = 0, *rCg = 0;
      if (t == 3) { j = 1; lH = bufs + 256; lHs = BS_; rH = bufs + 512; rHs = BS_;
                    lcase = 0; lCg = bufs + 256; rCg = bufs + 512; }
      else if (t == 126) { j = 63; lH = bufs; lHs = BS_; rH = A.hRc + (62 & 1) * 262144; rHs = 0;
                    lcase = 2; lCg = bufs; }
      else { int i2 = (t - 3) / 2; j = i2 + 1; lH = A.hRc + (size_t)(i2 & 1) * 262144; lHs = 0;
             rH = bufs + (i2 + 2) * 256; rHs = BS_; lcase = 1; rCg = bufs + (i2 + 2) * 256; }

      Frag8 fL, fR, fT;
      if (lcase == 0) {
        plain8(fL, lH + grow * lHs + 8 * lq);
        plain8(fR, rH + grow * rHs + 8 * lq);
        ldsys8(fT, thout + coff0);
      } else if (lcase == 2) {
        plain8(fL, lH + grow * lHs + 8 * lq);
        ldsys8(fR, rH + coff0);
        ldsys8(fT, thout + coff0);
      } else {
        plain8(fR, rH + grow * rHs + 8 * lq);
        ldsys8(fL, lH + coff0);
        ldsys8(fT, thout + coff0);
      }

      f32x4 acc2[5] = { {0.f,0.f,0.f,0.f}, {0.f,0.f,0.f,0.f}, {0.f,0.f,0.f,0.f},
                        {0.f,0.f,0.f,0.f}, {0.f,0.f,0.f,0.f} };
      const Frag8* fr[3] = { &fL, &fR, &fT };
      const u16* wch[3] = { A.w_lB, A.w_rB, A.w_tB };
#pragma unroll
      for (int ch = 0; ch < 3; ++ch) {
        const u16* wb = wch[ch];
#pragma unroll
        for (int kk = 0; kk < 8; ++kk) {
          U16x8 avv; avv.u = fr[ch]->v[kk];
#pragma unroll
          for (int ct = 0; ct < 5; ++ct) {
            U16x8 bv; bv.u = *(const uint4*)(wb + (size_t)(ct * 256 + c) * 256 + kk * 32 + 8 * lq);
            acc2[ct] = __builtin_amdgcn_mfma_f32_16x16x32_bf16(avv.s, bv.s, acc2[ct], 0, 0, 0);
          }
        }
      }
      u16* oH = A.hRc + (size_t)(j & 1) * 262144;
      float hv4[4];
#pragma unroll
      for (int i = 0; i < 4; ++i) {
        int row = erow0 + i;
        float a_ = acc2[0][i] + br[0];
        float ig = acc2[1][i] + br[1];
        float f1g = acc2[2][i] + br[2];
        float f2g = acc2[3][i] + br[3];
        float og = acc2[4][i] + br[4];
        float lc = (lcase == 1) ? rcv[i] : b2f(lCg[(size_t)row * BS_ + c]);
        float rc = (lcase == 2) ? rcv[i] : b2f(rCg[(size_t)row * BS_ + c]);
        float cn = tanh_(a_) * sig_(ig) + sig_(f1g) * lc + sig_(f2g) * rc;
        float hn = sig_(og) * tanh_(cn);
        rcv[i] = cn;
        Th[(wv * 16 + lq * 4 + i) * 24 + l15] = f2b(hn);
        hv4[i] = hn;
      }
      // per-block head-logit partials (plain stores; disjoint ownership; kfin reduces)
      float pr[12];
#pragma unroll
      for (int o = 0; o < 3; ++o)
#pragma unroll
        for (int i = 0; i < 4; ++i) pr[o * 4 + i] = hv4[i] * wo[o];
#pragma unroll
      for (int u = 0; u < 12; ++u)
#pragma unroll
        for (int mm = 1; mm < 16; mm <<= 1) pr[u] += __shfl_xor(pr[u], mm);
      if (l15 == 0) {
        float* lgo = A.lgp + (size_t)((j - 1) * 16 + n) * 3072;
#pragma unroll
        for (int o = 0; o < 3; ++o)
#pragma unroll
          for (int i = 0; i < 4; ++i)
            lgo[(size_t)(erow0 + i) * 3 + o] = pr[o * 4 + i];
      }
      __syncthreads();
      {  // coalesced coherent store of this block's 64x16 hR tile
        int r = tid >> 2, q = tid & 3;
        u64 vv = *(const u64*)(Th + r * 24 + q * 4);
        stsys8(oH + ((size_t)n * 1024 + m * 64 + r) * 16 + q * 4, vv);
      }
      ++bk; groupbar(bcnt, bgen, bk);
    }
  }
}

// ---------- finalize outs1: sum 16 per-block partials, log-softmax ----------
__global__ __launch_bounds__(256) void kfin(const float* __restrict__ lgp,
    const float* __restrict__ b_out, float* __restrict__ out1)
{
  int r = blockIdx.x * 256 + threadIdx.x;
  if (r >= 64512) return;
  int j = r >> 10, row = r & 1023;
  float l0 = b_out[0], l1 = b_out[1], l2 = b_out[2];
#pragma unroll
  for (int nn = 0; nn < 16; ++nn) {
    const float* p = lgp + ((size_t)(j * 16 + nn) * 1024 + row) * 3;
    l0 += p[0]; l1 += p[1]; l2 += p[2];
  }
  float m = fmaxf(l0, fmaxf(l1, l2));
  float lse = m + __logf(__expf(l0 - m) + __expf(l1 - m) + __expf(l2 - m));
  out1[r * 3 + 0] = l0 - lse;
  out1[r * 3 + 1] = l1 - lse;
  out1[r * 3 + 2] = l2 - lse;
}

extern "C" void kernel_launch(void* const* d_in, const int* in_sizes, int n_in,
                              void* d_out, int out_size, void* d_ws, size_t ws_size,
                              hipStream_t stream) {
  const int* tokens   = (const int*)d_in[0];
  const float* embed  = (const float*)d_in[2];
  const float* w_in   = (const float*)d_in[3];
  const float* b_in   = (const float*)d_in[4];
  const float* left_w = (const float*)d_in[5];
  const float* left_b = (const float*)d_in[6];
  const float* right_w= (const float*)d_in[7];
  const float* track_w= (const float*)d_in[8];
  const float* w_ih   = (const float*)d_in[9];
  const float* w_hh   = (const float*)d_in[10];
  const float* b_ih   = (const float*)d_in[11];
  const float* b_hh   = (const float*)d_in[12];
  const float* w_out  = (const float*)d_in[13];
  const float* b_out  = (const float*)d_in[14];
  float* out = (float*)d_out;

  char* ws = (char*)d_ws;
  u16* wB    = (u16*)ws;                      // bf16 weight pool (4 MB)
  u16* w_inB = wB;
  u16* w_ihB = wB + 65536;
  u16* w_hhB = wB + 851968;
  u16* w_lB  = wB + 1114112;
  u16* w_rB  = wB + 1441792;
  u16* w_tB  = wB + 1769472;
  u16* buf_s = (u16*)(ws + 4194304);          // [1024][65][256] bf16
  u16* padv  = (u16*)(ws + 38273024);         // [256] bf16
  u16* thc   = (u16*)(ws + 38273536);         // [2] chunked th, 512 KB each
  u16* hRc   = (u16*)(ws + 39322112);         // [2] chunked hR, 512 KB each
  unsigned* bar = (unsigned*)(ws + 40370688); // 16 groups x {cnt,gen}
  float* lgp = (float*)(ws + 40374784);       // [63][16][1024][3] f32 partials

  kprep<<<8192, 256, 0, stream>>>(w_in, w_ih, w_hh, left_w, right_w, track_w, wB);
  kinit<<<4, 256, 0, stream>>>(bar);
  kbuf2<<<2032, 256, 0, stream>>>(tokens, embed, w_inB, b_in, w_out, b_out, out, buf_s, padv);

  SeqArgs sa;
  sa.buf_s = buf_s; sa.padv = padv; sa.hRc = hRc; sa.thc = thc;
  sa.w_ihB = w_ihB; sa.w_hhB = w_hhB;
  sa.w_lB = w_lB; sa.w_rB = w_rB; sa.w_tB = w_tB;
  sa.b_ih = b_ih; sa.b_hh = b_hh; sa.b_l = left_b;
  sa.w_out = w_out; sa.lgp = lgp;
  sa.bar = bar;
  void* kargs[] = { &sa };
  hipLaunchCooperativeKernel((const void*)kseq, dim3(256), dim3(256), kargs, 0, stream);

  kfin<<<252, 256, 0, stream>>>(lgp, b_out, out + 390144);
}